// Round 5
// baseline (2056.186 us; speedup 1.0000x reference)
//
#include <hip/hip_runtime.h>
#include <hip/hip_fp16.h>

// Problem dims
#define H     1024
#define NIN   128
#define NOUT  128
#define BATCH 64
#define SEQ   512
#define MROWS (BATCH * SEQ)   // 32768

typedef _Float16 half8  __attribute__((ext_vector_type(8)));
typedef _Float16 half4v __attribute__((ext_vector_type(4)));
typedef float    f32x4  __attribute__((ext_vector_type(4)));
typedef unsigned uint4v __attribute__((ext_vector_type(4)));
typedef unsigned long long u64;

// ---------------------------------------------------------------------------
// f32 -> f16 conversion (vectorized, 4 elems/thread)
// ---------------------------------------------------------------------------
__global__ void cvt16_kernel(const float* __restrict__ src,
                             _Float16* __restrict__ dst, int n4) {
  int i = blockIdx.x * blockDim.x + threadIdx.x;
  if (i < n4) {
    float4 v = reinterpret_cast<const float4*>(src)[i];
    half4v h = {(_Float16)v.x, (_Float16)v.y, (_Float16)v.z, (_Float16)v.w};
    *reinterpret_cast<half4v*>(dst + (size_t)i * 4) = h;
  }
}

// ---------------------------------------------------------------------------
// biases + zero the ring buffers; ws is poisoned 0xAA before every timed call
// so this runs every call.
// ---------------------------------------------------------------------------
__global__ void init_misc_kernel(const float* __restrict__ b_ih0,
                                 const float* __restrict__ b_hh0,
                                 const float* __restrict__ b_ih1,
                                 const float* __restrict__ b_hh1,
                                 float* __restrict__ bias0,
                                 float* __restrict__ bias1,
                                 unsigned* __restrict__ zero_base,
                                 int zero_words) {
  int i = blockIdx.x * blockDim.x + threadIdx.x;
  if (i < H) {
    bias0[i] = b_ih0[i] + b_hh0[i];
    bias1[i] = b_ih1[i] + b_hh1[i];
  }
  for (int j = i; j < zero_words; j += gridDim.x * blockDim.x) zero_base[j] = 0u;
}

// ---------------------------------------------------------------------------
// Generic f16 MFMA GEMM, C[m][n] = sum_k A[m][k]*B[n][k] + bias[n]  (fp32 out)
// (unchanged — not the bottleneck)
// ---------------------------------------------------------------------------
__global__ __launch_bounds__(256) void gemm_f16_kernel(
    const _Float16* __restrict__ A, const _Float16* __restrict__ B,
    const float* __restrict__ bias, float* __restrict__ C,
    int M, int N, int K) {
  __shared__ _Float16 As[128][40];
  __shared__ _Float16 Bs[128][40];
  const int m0 = blockIdx.x * 128;
  const int n0 = blockIdx.y * 128;
  const int tid = threadIdx.x;
  const int wave = tid >> 6, lane = tid & 63;
  const int wm = (wave >> 1) * 64, wn = (wave & 1) * 64;
  const int fr = lane & 15;
  const int kg = (lane >> 4) * 8;

  f32x4 acc[4][4] = {};
  for (int k0 = 0; k0 < K; k0 += 32) {
    __syncthreads();
    for (int c = tid; c < 512; c += 256) {
      int row = c >> 2, ko = (c & 3) * 8;
      *reinterpret_cast<half8*>(&As[row][ko]) =
          *reinterpret_cast<const half8*>(&A[(size_t)(m0 + row) * K + k0 + ko]);
      *reinterpret_cast<half8*>(&Bs[row][ko]) =
          *reinterpret_cast<const half8*>(&B[(size_t)(n0 + row) * K + k0 + ko]);
    }
    __syncthreads();
    half8 af[4], bf[4];
#pragma unroll
    for (int i = 0; i < 4; ++i)
      af[i] = *reinterpret_cast<const half8*>(&As[wm + i * 16 + fr][kg]);
#pragma unroll
    for (int j = 0; j < 4; ++j)
      bf[j] = *reinterpret_cast<const half8*>(&Bs[wn + j * 16 + fr][kg]);
#pragma unroll
    for (int i = 0; i < 4; ++i)
#pragma unroll
      for (int j = 0; j < 4; ++j)
        acc[i][j] = __builtin_amdgcn_mfma_f32_16x16x32_f16(af[i], bf[j],
                                                           acc[i][j], 0, 0, 0);
  }
  const int lr = (lane >> 4) * 4, lc = lane & 15;
#pragma unroll
  for (int j = 0; j < 4; ++j) {
    int n = n0 + wn + j * 16 + lc;
    float bn = bias ? bias[n] : 0.0f;
#pragma unroll
    for (int i = 0; i < 4; ++i) {
      int m = m0 + wm + i * 16 + lr;
#pragma unroll
      for (int r = 0; r < 4; ++r)
        C[(size_t)(m + r) * N + n] = acc[i][j][r] + bn;
    }
  }
}

// ---------------------------------------------------------------------------
// Recurrent scan, fast-ring steady state + timeout-recovery fallback.
//
// Units: 8B = (lo32: 2x f16 h | hi32: step tag). 8B aligned stores are
// single-copy atomic -> tag-valid => data-valid. Tags monotone per slot, so
// stale reads only show OLDER tags (never false positive).
//
// Steady state: producers store fast ring only (sc0 -> local L2); consumers
// poll with plain sc0 loads (hit the same L2 when cluster is same-XCD, which
// blk&15 clustering gives under round-robin dispatch). No sc1 traffic at all.
//
// Placement safety: if a consumer wave times out (F_ITERS fast polls), it
// RECOVERS: copies its WG's entire 128-unit range, BOTH slots, fast->slow
// ring (sc1, tags intact), sets a WG-sticky dual-mode flag (LDS), and polls
// the slow ring from then on. Dual mode makes all future stores go to both
// rings. A stuck WG stalls the whole cluster within <=2 steps (depth-2 ring),
// so every WG times out, recovers, and the cluster converges to all-dual =
// R4-proven protocol. Correctness and liveness are placement-independent;
// only speed depends on placement.
// ---------------------------------------------------------------------------
#define NCLUST  16
#define GB      4
#define UNITS   2048   // 4 rows x 1024 halfs / 2 halfs per unit
#define F_ITERS 24

__global__ __launch_bounds__(256, 1) void scan_kernel(
    const float* __restrict__ xp,      // [BATCH][SEQ][H] fp32
    const _Float16* __restrict__ W16,  // [H][H] row = out col, contiguous K
    u64* __restrict__ fastbuf,         // [NCLUST][2][UNITS] (zeroed)
    u64* __restrict__ slowbuf,         // [NCLUST][2][UNITS] (zeroed)
    _Float16* __restrict__ hs_out,     // layer0: [BATCH][SEQ][H] f16, else null
    float* __restrict__ h_last)        // layer1: [BATCH][H] f32, else null
{
  __shared__ unsigned lds_h[2][UNITS];   // 16KB double buffer
  __shared__ int lds_mode;               // WG-sticky dual-mode flag

  const int blk = blockIdx.x;
  const int cluster = blk & (NCLUST - 1);
  const int rank = blk >> 4;
  const int tid = threadIdx.x;
  const int wave = tid >> 6;
  const int lane = tid & 63;
  const int fr = lane & 15;
  const int g = lane >> 4;             // k-group 0..3
  const int kg8 = g * 8;
  const int wcol = rank * 64 + wave * 16;
  const int c0 = wcol + g * 4;         // this lane's 4 out cols
  const int rb = lane & 15;            // batch row (valid if <GB)
  const bool act = rb < GB;

  if (tid == 0) lds_mode = 0;

  // W_hh A-fragment slice -> registers (unified VGPR/AGPR file)
  f32x4 wfrag[32];
#pragma unroll
  for (int kt = 0; kt < 32; ++kt) {
    wfrag[kt] = *reinterpret_cast<const f32x4*>(
        &W16[(size_t)(wcol + fr) * H + kt * 32 + kg8]);
    asm volatile("" : "+v"(wfrag[kt]));
  }
  __syncthreads();   // orders lds_mode init before any recovery write

  u64* fcl = fastbuf + (size_t)cluster * (2 * UNITS);
  u64* scl = slowbuf + (size_t)cluster * (2 * UNITS);
  const int b0 = cluster * GB;

  // producer unit index (even => 16B-aligned pair {w0, w0+1})
  const int w0 = (c0 >> 5) * 64 + rb * 16 + (((c0 >> 3) & 3) << 2) +
                 ((c0 >> 1) & 3);

  bool mode = false;   // false = fast-only; true = dual (sticky)

  // xp prefetch, one step ahead
  float4 xpv = {0.f, 0.f, 0.f, 0.f};
  if (act)
    xpv = *reinterpret_cast<const float4*>(
        &xp[((size_t)(b0 + rb) * SEQ + 0) * H + c0]);

  for (int t = 0; t < SEQ; ++t) {
    uint4v q0, q1, q2, q3;
    if (t > 0) {
      const unsigned tag = (unsigned)t;
      const char* fb = (const char*)(fcl + (size_t)(t & 1) * UNITS) +
                       (size_t)tid * 16;
      const char* sb = (const char*)(scl + (size_t)(t & 1) * UNITS) +
                       (size_t)tid * 16;
      bool got = false;
      if (!mode) {
        // ---- fast poll: plain sc0 loads (L2-hit path, no nt) ----
        for (int it = 0; it < F_ITERS; ++it) {
          asm volatile(
              "global_load_dwordx4 %0, %4, off sc0\n\t"
              "global_load_dwordx4 %1, %5, off sc0\n\t"
              "global_load_dwordx4 %2, %6, off sc0\n\t"
              "global_load_dwordx4 %3, %7, off sc0\n\t"
              "s_waitcnt vmcnt(0)"
              : "=&v"(q0), "=&v"(q1), "=&v"(q2), "=&v"(q3)
              : "v"(fb), "v"(fb + 4096), "v"(fb + 8192), "v"(fb + 12288)
              : "memory");
          bool ok = (q0.y == tag) & (q0.w == tag) & (q1.y == tag) &
                    (q1.w == tag) & (q2.y == tag) & (q2.w == tag) &
                    (q3.y == tag) & (q3.w == tag);
          if (__ballot(ok) == ~0ull) { got = true; break; }
        }
        if (!got) {
          // ---- recovery: publish my WG's units (both slots) to slow ring
          const int base = 128 * rank + lane * 2;
#pragma unroll
          for (int s2 = 0; s2 < 2; ++s2) {
            uint4v d;
            const u64* srcp = fcl + (size_t)s2 * UNITS + base;
            u64* dstp = scl + (size_t)s2 * UNITS + base;
            asm volatile(
                "global_load_dwordx4 %0, %1, off sc0\n\t"
                "s_waitcnt vmcnt(0)"
                : "=&v"(d) : "v"(srcp) : "memory");
            asm volatile("global_store_dwordx4 %0, %1, off sc0 sc1"
                         :: "v"(dstp), "v"(d) : "memory");
          }
          asm volatile("s_waitcnt vmcnt(0)" ::: "memory");
          if (lane == 0) lds_mode = 1;
          mode = true;
        }
      }
      if (!got) {
        // ---- slow poll (system-visible ring) ----
        while (true) {
          asm volatile(
              "global_load_dwordx4 %0, %4, off sc0 sc1\n\t"
              "global_load_dwordx4 %1, %5, off sc0 sc1\n\t"
              "global_load_dwordx4 %2, %6, off sc0 sc1\n\t"
              "global_load_dwordx4 %3, %7, off sc0 sc1\n\t"
              "s_waitcnt vmcnt(0)"
              : "=&v"(q0), "=&v"(q1), "=&v"(q2), "=&v"(q3)
              : "v"(sb), "v"(sb + 4096), "v"(sb + 8192), "v"(sb + 12288)
              : "memory");
          bool ok = (q0.y == tag) & (q0.w == tag) & (q1.y == tag) &
                    (q1.w == tag) & (q2.y == tag) & (q2.w == tag) &
                    (q3.y == tag) & (q3.w == tag);
          if (__ballot(ok) == ~0ull) break;
          __builtin_amdgcn_s_sleep(2);
        }
      }
    }

    // issue next step's xp prefetch (hidden under LDS+MFMA+epilogue)
    float4 xpn = {0.f, 0.f, 0.f, 0.f};
    {
      int t2 = (t + 1 < SEQ) ? (t + 1) : (SEQ - 1);
      if (act)
        xpn = *reinterpret_cast<const float4*>(
            &xp[((size_t)(b0 + rb) * SEQ + t2) * H + c0]);
    }

    f32x4 s = {0.f, 0.f, 0.f, 0.f};
    if (t > 0) {
      // stage polled units to LDS (double-buffered)
      unsigned* lb_w = lds_h[t & 1];
#pragma unroll
      for (int j = 0; j < 4; ++j) {
        uint4v q = (j == 0) ? q0 : (j == 1) ? q1 : (j == 2) ? q2 : q3;
        u64 pk = (u64)q.x | ((u64)q.z << 32);
        *reinterpret_cast<u64*>(&lb_w[tid * 2 + j * 512]) = pk;
      }
      __syncthreads();
      mode = mode | (lds_mode != 0);   // WG-uniform sticky dual mode

      // ---- MFMA: D = W(64x1024) . h^T ----
      const char* lb = reinterpret_cast<const char*>(lds_h[t & 1]);
      f32x4 acc[4] = {{0.f, 0.f, 0.f, 0.f}, {0.f, 0.f, 0.f, 0.f},
                      {0.f, 0.f, 0.f, 0.f}, {0.f, 0.f, 0.f, 0.f}};
#pragma unroll
      for (int kt = 0; kt < 32; ++kt) {
        half8 hf = *reinterpret_cast<const half8*>(
            lb + kt * 256 + (rb & 3) * 64 + g * 16);
        acc[kt & 3] = __builtin_amdgcn_mfma_f32_16x16x32_f16(
            __builtin_bit_cast(half8, wfrag[kt]), hf, acc[kt & 3], 0, 0, 0);
      }
      s = (acc[0] + acc[1]) + (acc[2] + acc[3]);
    }

    if (act) {
      union { u64 u; _Float16 h[4]; unsigned w[2]; } pk;
      float hv[4];
#pragma unroll
      for (int r = 0; r < 4; ++r) {
        float v = s[r] + xpv[r];
        v = fminf(fmaxf(v, -15.f), 15.f);
        float e = __expf(2.f * v);                          // e = exp(2v)
        hv[r] = 1.f - 2.f * __builtin_amdgcn_rcpf(e + 1.f); // tanh(v)
        pk.h[r] = (_Float16)hv[r];
      }
      if (t < SEQ - 1) {
        const unsigned tagw = (unsigned)(t + 1);
        uint4v sv = {pk.w[0], tagw, pk.w[1], tagw};
        u64* fdst = fcl + ((t + 1) & 1) * UNITS + w0;
        if (!mode) {
          asm volatile("global_store_dwordx4 %0, %1, off sc0"
                       :: "v"(fdst), "v"(sv) : "memory");
        } else {
          u64* sdst = scl + ((t + 1) & 1) * UNITS + w0;
          asm volatile(
              "global_store_dwordx4 %0, %2, off sc0\n\t"
              "global_store_dwordx4 %1, %2, off sc0 sc1"
              :: "v"(fdst), "v"(sdst), "v"(sv) : "memory");
        }
      }
      if (hs_out) {
        *reinterpret_cast<u64*>(
            &hs_out[((size_t)(b0 + rb) * SEQ + t) * H + c0]) = pk.u;
      } else if (t == SEQ - 1) {
        float4 o = {hv[0], hv[1], hv[2], hv[3]};
        *reinterpret_cast<float4*>(&h_last[(size_t)(b0 + rb) * H + c0]) = o;
      }
    }
    xpv = xpn;
  }
}

// ---------------------------------------------------------------------------
// Final FC: out[b][n] = h_last[b] . W_fc[n] + b_fc[n], one wave per output.
// ---------------------------------------------------------------------------
__global__ __launch_bounds__(256) void fc_kernel(
    const float* __restrict__ h_last, const float* __restrict__ W_fc,
    const float* __restrict__ b_fc, float* __restrict__ out) {
  const int wave = threadIdx.x >> 6, lane = threadIdx.x & 63;
  const int o = blockIdx.x * 4 + wave;  // 0..8191
  const int b = o >> 7, n = o & 127;
  const float* hr = h_last + (size_t)b * H;
  const float* wr = W_fc + (size_t)n * H;
  float s = 0.0f;
  for (int k = lane; k < H; k += 64) s += hr[k] * wr[k];
#pragma unroll
  for (int off = 32; off; off >>= 1) s += __shfl_down(s, off);
  if (lane == 0) out[o] = s + b_fc[n];
}

// ---------------------------------------------------------------------------
extern "C" void kernel_launch(void* const* d_in, const int* in_sizes, int n_in,
                              void* d_out, int out_size, void* d_ws,
                              size_t ws_size, hipStream_t stream) {
  (void)in_sizes; (void)n_in; (void)out_size; (void)ws_size;
  const float* x     = (const float*)d_in[0];
  const float* W_ih0 = (const float*)d_in[1];
  const float* b_ih0 = (const float*)d_in[2];
  const float* W_hh0 = (const float*)d_in[3];
  const float* b_hh0 = (const float*)d_in[4];
  const float* W_ih1 = (const float*)d_in[5];
  const float* b_ih1 = (const float*)d_in[6];
  const float* W_hh1 = (const float*)d_in[7];
  const float* b_hh1 = (const float*)d_in[8];
  const float* W_fc  = (const float*)d_in[9];
  const float* b_fc  = (const float*)d_in[10];
  float* out = (float*)d_out;

  char* ws = (char*)d_ws;
  size_t off = 0;
  auto carve = [&](size_t bytes) {
    char* p = ws + off;
    off += (bytes + 255) & ~(size_t)255;
    return p;
  };
  float*    xpbuf   = (float*)   carve((size_t)MROWS * H * 4);  // 134 MB
  _Float16* hs0_16  = (_Float16*)carve((size_t)MROWS * H * 2);  //  67 MB
  _Float16* x16     = (_Float16*)carve((size_t)MROWS * NIN * 2);
  _Float16* wih0_16 = (_Float16*)carve((size_t)H * NIN * 2);
  _Float16* whh0_16 = (_Float16*)carve((size_t)H * H * 2);
  _Float16* wih1_16 = (_Float16*)carve((size_t)H * H * 2);
  _Float16* whh1_16 = (_Float16*)carve((size_t)H * H * 2);
  float*    bias0   = (float*)   carve(H * 4);
  float*    bias1   = (float*)   carve(H * 4);
  // zero region: [fb0 | fb1 | sb0 | sb1] contiguous, 512KB each
  const size_t RING = (size_t)NCLUST * 2 * UNITS * 8;
  u64*      fb0     = (u64*)     carve(RING);
  u64*      fb1     = (u64*)     carve(RING);
  u64*      sb0     = (u64*)     carve(RING);
  u64*      sb1     = (u64*)     carve(RING);
  float*    h_lastp = (float*)   carve((size_t)BATCH * H * 4);

  const int zero_words = (int)(RING * 4 / 4);

  // 1. biases + zero rings
  init_misc_kernel<<<(zero_words + 255) / 256, 256, 0, stream>>>(
      b_ih0, b_hh0, b_ih1, b_hh1, bias0, bias1, (unsigned*)fb0, zero_words);

  // 2. f16 conversions
  cvt16_kernel<<<(MROWS * NIN / 4 + 255) / 256, 256, 0, stream>>>(x, x16,
                                                                  MROWS * NIN / 4);
  cvt16_kernel<<<(H * NIN / 4 + 255) / 256, 256, 0, stream>>>(W_ih0, wih0_16,
                                                              H * NIN / 4);
  cvt16_kernel<<<(H * H / 4 + 255) / 256, 256, 0, stream>>>(W_hh0, whh0_16,
                                                            H * H / 4);
  cvt16_kernel<<<(H * H / 4 + 255) / 256, 256, 0, stream>>>(W_ih1, wih1_16,
                                                            H * H / 4);
  cvt16_kernel<<<(H * H / 4 + 255) / 256, 256, 0, stream>>>(W_hh1, whh1_16,
                                                            H * H / 4);

  // 3. xp0 = x @ W_ih0^T + (b_ih0 + b_hh0)
  {
    dim3 grid(MROWS / 128, H / 128);
    gemm_f16_kernel<<<grid, 256, 0, stream>>>(x16, wih0_16, bias0, xpbuf,
                                              MROWS, H, NIN);
  }

  // 4. layer-0 scan
  {
    const float* xp_p = xpbuf; const _Float16* w_p = whh0_16;
    u64* fb_p = fb0; u64* sb_p = sb0;
    _Float16* hs_p = hs0_16; float* hl_p = nullptr;
    void* args[] = {&xp_p, &w_p, &fb_p, &sb_p, &hs_p, &hl_p};
    hipLaunchCooperativeKernel((const void*)scan_kernel, dim3(256), dim3(256),
                               args, 0, stream);
  }

  // 5. xp1 = hs0 @ W_ih1^T + (b_ih1 + b_hh1)
  {
    dim3 grid(MROWS / 128, H / 128);
    gemm_f16_kernel<<<grid, 256, 0, stream>>>(hs0_16, wih1_16, bias1, xpbuf,
                                              MROWS, H, H);
  }

  // 6. layer-1 scan (keeps only final h)
  {
    const float* xp_p = xpbuf; const _Float16* w_p = whh1_16;
    u64* fb_p = fb1; u64* sb_p = sb1;
    _Float16* hs_p = nullptr; float* hl_p = h_lastp;
    void* args[] = {&xp_p, &w_p, &fb_p, &sb_p, &hs_p, &hl_p};
    hipLaunchCooperativeKernel((const void*)scan_kernel, dim3(256), dim3(256),
                               args, 0, stream);
  }

  // 7. out = h_last @ W_fc^T + b_fc
  fc_kernel<<<BATCH * NOUT / 4, 256, 0, stream>>>(h_lastp, W_fc, b_fc, out);
}